// Round 4
// baseline (50.111 us; speedup 1.0000x reference)
//
#include <hip/hip_runtime.h>
#include <math.h>

namespace {
constexpr int Bn = 8192, Pn = 128, Dn = 128;
constexpr float MAXN = 1.0f - 1e-5f;              // (1-PROJ_EPS)/sqrt(c)
constexpr float CLAMPV = 16.63553233343869f;      // log(2/eps32)
constexpr float SMOOTH = 50.0f;
}

// ---------------- per-p prep: projected bias, per-p params, and the
// interleaved transposed table wbt[p>>3][k][16] = (w[p][k] | bias_proj[p][k])
__global__ void prep_p_kernel(const float* __restrict__ weight,
                              const float* __restrict__ bias,
                              float* __restrict__ wbt,
                              float* __restrict__ pp) {
  const int p = blockIdx.x;
  const int lane = threadIdx.x;  // 0..63
  const float* br = bias + p * Dn;
  const float* wr = weight + p * Dn;
  float b0 = br[lane], b1 = br[lane + 64];
  float w0 = wr[lane], w1 = wr[lane + 64];
  double nb2 = (double)b0 * b0 + (double)b1 * b1;
#pragma unroll
  for (int off = 32; off; off >>= 1) nb2 += __shfl_xor(nb2, off);
  double norm = sqrt(nb2);
  if (norm < 1e-15) norm = 1e-15;
  double scl = (norm > (double)MAXN) ? (double)MAXN / norm : 1.0;
  float bp0 = (float)((double)b0 * scl);
  float bp1 = (float)((double)b1 * scl);
  // wbt: [pt=p>>3][k=0..127][16]; slot j=p&7 -> w, j+8 -> bias_proj
  size_t base = (size_t)(p >> 3) * (Dn * 16) + (p & 7);
  wbt[base + (size_t)lane * 16]            = w0;
  wbt[base + (size_t)(lane + 64) * 16]     = w1;
  wbt[base + (size_t)lane * 16 + 8]        = bp0;
  wbt[base + (size_t)(lane + 64) * 16 + 8] = bp1;

  double p2 = nb2 * scl * scl;
  double cx = 1.0 - p2;                 // coef_x = 1 - c*||p||^2
  double bwl = (double)bp0 * w0 + (double)bp1 * w1;
  double w2l = (double)w0 * w0 + (double)w1 * w1;
#pragma unroll
  for (int off = 32; off; off >>= 1) {
    bwl += __shfl_xor(bwl, off);
    w2l += __shfl_xor(w2l, off);
  }
  if (lane == 0) {
    double an = cx * sqrt(w2l);         // ||a|| = (1-p2)*||w||
    if (an < 1e-15) an = 1e-15;
    pp[p]          = (float)cx;
    pp[Pn + p]     = (float)bwl;        // <bias_proj, w>
    pp[2 * Pn + p] = (float)(1.0 / an);
    pp[3 * Pn + p] = (float)(2.0 / cx * an);  // lambda_p * a_norm
  }
}

// ---------------- per-b prep: x2 and 2/(1-x2), f64-accurate (1-x2 ~ 2e-5)
__global__ void prep_x_kernel(const float* __restrict__ x, float* __restrict__ xb) {
  const int row = blockIdx.x * 4 + (threadIdx.x >> 6);
  const int lane = threadIdx.x & 63;
  const float* xr = x + row * Dn;
  float x0 = xr[lane], x1 = xr[lane + 64];
  double s = (double)x0 * x0 + (double)x1 * x1;
#pragma unroll
  for (int off = 32; off; off >>= 1) s += __shfl_xor(s, off);
  if (lane == 0) {
    xb[row] = (float)s;
    xb[Bn + row] = (float)(2.0 / (1.0 - s));
  }
}

// ---------------- main: lane-per-b-row, wave-uniform p-tile of 8.
// w/bp operands are lane-uniform -> SGPRs via s_load_dwordx16 (scalar cache),
// x staged per-wave in LDS (8KB, XOR-swizzled, zero barriers), pipelined G-loads.
__global__ __launch_bounds__(256)
void main_kernel(const float* __restrict__ x,
                 const float* __restrict__ wbt,
                 const float* __restrict__ pp,
                 const float* __restrict__ xb,
                 float* __restrict__ out) {
  __shared__ float4 xs4[4][64][8];      // [wave][row][k-chunk float4], swizzled
  const int tid = threadIdx.x;
  const int wid = tid >> 6;
  const int l = tid & 63;
  const int lsw = l & 7;
  const int p0 = blockIdx.y * 8;
  const int R0 = blockIdx.x * 256 + wid * 64;   // wave's first b-row
  const float* __restrict__ wb = wbt + (size_t)blockIdx.y * (Dn * 16);

  const int srow = l >> 3;              // staging: 8 rows x 8 float4 per pass
  const int scol = l & 7;

  float accw[8] = {0.f, 0.f, 0.f, 0.f, 0.f, 0.f, 0.f, 0.f};
  float accb[8] = {0.f, 0.f, 0.f, 0.f, 0.f, 0.f, 0.f, 0.f};

  auto GLOAD = [&](float4* g, int ch) {
#pragma unroll
    for (int ps = 0; ps < 8; ++ps) {
      int r = ps * 8 + srow;
      g[ps] = *reinterpret_cast<const float4*>(
          x + (size_t)(R0 + r) * Dn + ch * 32 + scol * 4);
    }
  };
  auto SWRITE = [&](const float4* g) {
#pragma unroll
    for (int ps = 0; ps < 8; ++ps) {
      int r = ps * 8 + srow;
      xs4[wid][r][scol ^ (r & 7)] = g[ps];
    }
  };
  auto FMACH = [&](int ch) {
#pragma unroll 2
    for (int q = 0; q < 8; ++q) {       // k4 steps within 32-k chunk
      float4 xk = xs4[wid][l][q ^ lsw];
      const float* wk = wb + (size_t)(ch * 32 + q * 4) * 16;  // uniform
      float xa[4] = {xk.x, xk.y, xk.z, xk.w};
#pragma unroll
      for (int kk = 0; kk < 4; ++kk) {
        const float* wkk = wk + kk * 16;  // 16 floats: 8 w | 8 bp (64B aligned)
#pragma unroll
        for (int j = 0; j < 8; ++j) {
          accw[j] = fmaf(wkk[j], xa[kk], accw[j]);
          accb[j] = fmaf(wkk[8 + j], xa[kk], accb[j]);
        }
      }
    }
  };

  // software pipeline: G-loads for chunk c+1 in flight during FMA of chunk c.
  float4 ga[8], gb[8];
  GLOAD(ga, 0);
  SWRITE(ga); GLOAD(gb, 1); FMACH(0);
  SWRITE(gb); GLOAD(ga, 2); FMACH(1);
  SWRITE(ga); GLOAD(gb, 3); FMACH(2);
  SWRITE(gb);               FMACH(3);

  // ---- epilogue: per-(b,p) scalar math (Mobius denominator cancels)
  const int b = R0 + l;
  const float x2i = xb[b];
  const float fbi = xb[Bn + b];
  float res[8];
#pragma unroll
  for (int j = 0; j < 8; ++j) {
    int p = p0 + j;
    float cx = pp[p], bw = pp[Pn + p], ia = pp[2 * Pn + p], so = pp[3 * Pn + p];
    float coefp = 1.0f + x2i - 2.0f * accb[j];   // 1 + 2c*dot + c*x2
    float X = cx * accw[j] - coefp * bw;
    float arg = X * fbi * ia;                    // den cancels analytically
    float z1 = SMOOTH * (arg + CLAMPV);
    float z2 = SMOOTH * (arg - CLAMPV);
    float sp1 = fmaxf(z1, 0.0f) + log1pf(expf(-fabsf(z1)));
    float sp2 = fmaxf(z2, 0.0f) + log1pf(expf(-fabsf(z2)));
    float argc = -CLAMPV + (sp1 - sp2) * (1.0f / SMOOTH);
    res[j] = so * asinhf(argc);
  }
  float* orow = out + (size_t)b * Pn + p0;
  *reinterpret_cast<float4*>(orow)     = make_float4(res[0], res[1], res[2], res[3]);
  *reinterpret_cast<float4*>(orow + 4) = make_float4(res[4], res[5], res[6], res[7]);
}

extern "C" void kernel_launch(void* const* d_in, const int* in_sizes, int n_in,
                              void* d_out, int out_size, void* d_ws, size_t ws_size,
                              hipStream_t stream) {
  const float* x = (const float*)d_in[0];
  const float* w = (const float*)d_in[1];
  const float* bias = (const float*)d_in[2];
  float* out = (float*)d_out;
  float* ws = (float*)d_ws;
  float* wbt = ws;                  // 16 * 128 * 16 floats (interleaved w|bp)
  float* pp = wbt + 16 * Dn * 16;   // 4*P per-p params
  float* xb = pp + 4 * Pn;          // 2*B per-b params

  hipLaunchKernelGGL(prep_p_kernel, dim3(Pn), dim3(64), 0, stream, w, bias, wbt, pp);
  hipLaunchKernelGGL(prep_x_kernel, dim3(Bn / 4), dim3(256), 0, stream, x, xb);
  hipLaunchKernelGGL(main_kernel, dim3(Bn / 256, Pn / 8), dim3(256), 0, stream,
                     x, wbt, pp, xb, out);
}